// Round 4
// baseline (180.209 us; speedup 1.0000x reference)
//
#include <hip/hip_runtime.h>
#include <math.h>

#define NF 32
#define NDOF 29
#define BLOCK 256            // 8 batches/block, 4 waves, no LDS, no barriers

__global__ __launch_bounds__(BLOCK) void fk_kernel(
    const float* __restrict__ ja,       // (B,29)
    const float* __restrict__ axes,     // (32,3)
    const float* __restrict__ origins,  // (32,4,4)
    const float* __restrict__ mmul,     // (2,)
    const float* __restrict__ moff,     // (2,)
    const int*   __restrict__ ctrl,     // (29,)
    const int*   __restrict__ msrc,     // (2,)
    const int*   __restrict__ mdst,     // (2,)
    const int*   __restrict__ types,    // (32,)
    float*       __restrict__ out,      // (B,32,4,4)
    int B)
{
    const int tid  = threadIdx.x;
    const int lane = tid & 63;          // lane within wave
    const int f    = tid & 31;          // frame handled by this lane
    const long b   = (long)blockIdx.x * (BLOCK / 32) + (tid >> 5);
    if (b >= (long)B) return;           // whole 32-groups only; shuffles stay in-group

    // ---- fold ctrl scatter + mimic into: angle = mu * ja[slot] + of ----
    int slot = -1;
    #pragma unroll
    for (int j = 0; j < NDOF; ++j) if (ctrl[j] == f) slot = j;
    float mu = 1.0f, of = 0.0f;
    #pragma unroll
    for (int m = 0; m < 2; ++m) {
        if (mdst[m] == f) {
            const int sf = msrc[m];
            #pragma unroll
            for (int j = 0; j < NDOF; ++j) if (ctrl[j] == sf) slot = j;
            mu = mmul[m]; of = moff[m];
        }
    }

    // ---- local motion matrix of frame f (Rodrigues / prismatic) ----
    const float a  = (slot >= 0) ? fmaf(mu, ja[b * NDOF + slot], of) : 0.0f;
    const float wx = a * axes[f * 3 + 0];
    const float wy = a * axes[f * 3 + 1];
    const float wz = a * axes[f * 3 + 2];
    const int   ty = types[f];

    float R0,R1,R2,R3,R4,R5,R6,R7,R8;
    if (ty == 1) {
        const float t2 = wx*wx + wy*wy + wz*wz;
        const float th = sqrtf(t2 + 1e-18f);
        const float inv = 1.0f / th;
        const float kx = wx*inv, ky = wy*inv, kz = wz*inv;
        float s, c;
        __sincosf(th, &s, &c);
        const float v = 1.0f - c;
        R0 = fmaf(v*kx, kx, c);
        R1 = v*kx*ky - s*kz;
        R2 = v*kx*kz + s*ky;
        R3 = v*kx*ky + s*kz;
        R4 = fmaf(v*ky, ky, c);
        R5 = v*ky*kz - s*kx;
        R6 = v*kx*kz - s*ky;
        R7 = v*ky*kz + s*kx;
        R8 = fmaf(v*kz, kz, c);
    } else {
        R0=1.f;R1=0.f;R2=0.f;R3=0.f;R4=1.f;R5=0.f;R6=0.f;R7=0.f;R8=1.f;
    }
    const float tx  = (ty == 2) ? wx : 0.0f;
    const float tyv = (ty == 2) ? wy : 0.0f;
    const float tz  = (ty == 2) ? wz : 0.0f;

    // M = origin_f @ motion_f   (3x4 affine, row-major M[r*4+c])
    float M[12];
    {
        const float4* O4 = (const float4*)origins;
        #pragma unroll
        for (int r = 0; r < 3; ++r) {
            const float4 O = O4[f * 4 + r];
            M[r*4+0] = O.x*R0 + O.y*R3 + O.z*R6;
            M[r*4+1] = O.x*R1 + O.y*R4 + O.z*R7;
            M[r*4+2] = O.x*R2 + O.y*R5 + O.z*R8;
            M[r*4+3] = O.x*tx + O.y*tyv + O.z*tz + O.w;
        }
    }

    // ---- pointer-jumping prefix composition over the kinematic tree ----
    // parent: 0 -> -1 ; 1..29 -> f-1 ; 30,31 -> 10.  depth <= 30 => 5 iters.
    int ptr = (f == 0) ? -1 : ((f >= 30) ? 10 : (f - 1));
    const int half = lane & 32;         // which 32-group of this wave

    #pragma unroll
    for (int it = 0; it < 5; ++it) {
        const int src = half | (ptr & 31);          // valid lane even if ptr<0
        float P[12];
        #pragma unroll
        for (int i = 0; i < 12; ++i) P[i] = __shfl(M[i], src, 64);
        const int pptr = __shfl(ptr, src, 64);
        if (ptr >= 0) {
            float N[12];
            #pragma unroll
            for (int r = 0; r < 3; ++r) {
                const float p0 = P[r*4+0], p1 = P[r*4+1], p2 = P[r*4+2], p3 = P[r*4+3];
                N[r*4+0] = p0*M[0] + p1*M[4] + p2*M[8];
                N[r*4+1] = p0*M[1] + p1*M[5] + p2*M[9];
                N[r*4+2] = p0*M[2] + p1*M[6] + p2*M[10];
                N[r*4+3] = p0*M[3] + p1*M[7] + p2*M[11] + p3;
            }
            #pragma unroll
            for (int i = 0; i < 12; ++i) M[i] = N[i];
            ptr = pptr;
        }
    }

    // ---- store: this lane owns exactly one 64-B line (4 consecutive f4) ----
    float4* o = (float4*)(out + b * 512 + f * 16);
    o[0] = make_float4(M[0], M[1], M[2],  M[3]);
    o[1] = make_float4(M[4], M[5], M[6],  M[7]);
    o[2] = make_float4(M[8], M[9], M[10], M[11]);
    o[3] = make_float4(0.0f, 0.0f, 0.0f,  1.0f);
}

extern "C" void kernel_launch(void* const* d_in, const int* in_sizes, int n_in,
                              void* d_out, int out_size, void* d_ws, size_t ws_size,
                              hipStream_t stream) {
    const float* ja   = (const float*)d_in[0];
    const float* axes = (const float*)d_in[1];
    const float* orig = (const float*)d_in[2];
    const float* mmul = (const float*)d_in[3];
    const float* moff = (const float*)d_in[4];
    const int*   ctrl = (const int*)d_in[5];
    const int*   msrc = (const int*)d_in[6];
    const int*   mdst = (const int*)d_in[7];
    const int*   typs = (const int*)d_in[8];
    float* out = (float*)d_out;

    const int B = in_sizes[0] / NDOF;
    const int batches_per_block = BLOCK / 32;
    const int grid = (B + batches_per_block - 1) / batches_per_block;
    fk_kernel<<<grid, BLOCK, 0, stream>>>(ja, axes, orig, mmul, moff,
                                          ctrl, msrc, mdst, typs, out, B);
}

// Round 5
// 163.581 us; speedup vs baseline: 1.1017x; 1.1017x over previous
//
#include <hip/hip_runtime.h>
#include <math.h>

#define NF 32
#define NDOF 29
#define BLOCK 256
#define SLOT_DW 20          // dwords per staged pose (80 B: 16-B aligned, ~conflict-free)

// N = A @ B for 3x4 affines (row-major [r*4+c], implicit bottom row 0001)
__device__ __forceinline__ void amul(float* __restrict__ N,
                                     const float* __restrict__ A,
                                     const float* __restrict__ B) {
    #pragma unroll
    for (int r = 0; r < 3; ++r) {
        const float a0 = A[r*4+0], a1 = A[r*4+1], a2 = A[r*4+2], a3 = A[r*4+3];
        N[r*4+0] = a0*B[0] + a1*B[4] + a2*B[8];
        N[r*4+1] = a0*B[1] + a1*B[5] + a2*B[9];
        N[r*4+2] = a0*B[2] + a1*B[6] + a2*B[10];
        N[r*4+3] = a0*B[3] + a1*B[7] + a2*B[11] + a3;
    }
}

__global__ __launch_bounds__(BLOCK) void fk_kernel(
    const float* __restrict__ ja,       // (B,29)
    const float* __restrict__ axes,     // (32,3)
    const float* __restrict__ origins,  // (32,4,4)
    const float* __restrict__ mmul,     // (2,)
    const float* __restrict__ moff,     // (2,)
    const int*   __restrict__ ctrl,     // (29,)
    const int*   __restrict__ msrc,     // (2,)
    const int*   __restrict__ mdst,     // (2,)
    const int*   __restrict__ types,    // (32,)
    float*       __restrict__ out,      // (B,32,4,4)
    int B)
{
    __shared__ float s_ax[NF][3];
    __shared__ float s_or[NF][12];
    __shared__ int   s_type[NF];
    __shared__ int   s_slot[NF];
    __shared__ float s_mult[NF];
    __shared__ float s_off[NF];
    __shared__ float s_stage[4][64 * SLOT_DW];   // per-wave staging

    const int tid  = threadIdx.x;
    const int lane = tid & 63;
    const int wv   = tid >> 6;
    const int sub  = lane & 7;          // segment index within batch group
    const int grp  = lane & ~7;         // 8-lane group base within wave

    if (tid < NF) {
        const int f = tid;
        s_ax[f][0] = axes[f*3+0];
        s_ax[f][1] = axes[f*3+1];
        s_ax[f][2] = axes[f*3+2];
        #pragma unroll
        for (int i = 0; i < 12; ++i) s_or[f][i] = origins[f*16 + i];
        s_type[f] = types[f];
        int slot = -1;
        for (int j = 0; j < NDOF; ++j) if (ctrl[j] == f) slot = j;
        float mu = 1.0f, of = 0.0f;
        for (int m = 0; m < 2; ++m) {
            if (mdst[m] == f) {
                const int sf = msrc[m];
                for (int j = 0; j < NDOF; ++j) if (ctrl[j] == sf) slot = j;
                mu = mmul[m]; of = moff[m];
            }
        }
        s_slot[f] = slot; s_mult[f] = mu; s_off[f] = of;
    }
    __syncthreads();   // only block barrier; precedes all global stores

    const long bat = (long)blockIdx.x * 32 + (tid >> 3);   // this group's batch
    const bool bok = bat < (long)B;

    // ---- pass 1: local matrices for my 4 frames ----
    float M[4][12];
    #pragma unroll
    for (int j = 0; j < 4; ++j) {
        const int f    = 4*sub + j;
        const int slot = s_slot[f];
        float a = 0.0f;
        if (slot >= 0 && bok) a = fmaf(s_mult[f], ja[bat * NDOF + slot], s_off[f]);
        const float wx = a * s_ax[f][0];
        const float wy = a * s_ax[f][1];
        const float wz = a * s_ax[f][2];
        const int ty = s_type[f];
        float R0,R1,R2,R3,R4,R5,R6,R7,R8;
        if (ty == 1) {
            const float t2 = wx*wx + wy*wy + wz*wz;
            const float th = sqrtf(t2 + 1e-18f);
            const float inv = 1.0f / th;
            const float kx = wx*inv, ky = wy*inv, kz = wz*inv;
            float s, c;
            __sincosf(th, &s, &c);
            const float v = 1.0f - c;
            R0 = fmaf(v*kx, kx, c);
            R1 = v*kx*ky - s*kz;
            R2 = v*kx*kz + s*ky;
            R3 = v*kx*ky + s*kz;
            R4 = fmaf(v*ky, ky, c);
            R5 = v*ky*kz - s*kx;
            R6 = v*kx*kz - s*ky;
            R7 = v*ky*kz + s*kx;
            R8 = fmaf(v*kz, kz, c);
        } else {
            R0=1.f;R1=0.f;R2=0.f;R3=0.f;R4=1.f;R5=0.f;R6=0.f;R7=0.f;R8=1.f;
        }
        const float tx  = (ty == 2) ? wx : 0.0f;
        const float tyv = (ty == 2) ? wy : 0.0f;
        const float tz  = (ty == 2) ? wz : 0.0f;
        const float* O = s_or[f];
        #pragma unroll
        for (int r = 0; r < 3; ++r) {
            const float o0 = O[r*4+0], o1 = O[r*4+1], o2 = O[r*4+2], o3 = O[r*4+3];
            M[j][r*4+0] = o0*R0 + o1*R3 + o2*R6;
            M[j][r*4+1] = o0*R1 + o1*R4 + o2*R7;
            M[j][r*4+2] = o0*R2 + o1*R5 + o2*R8;
            M[j][r*4+3] = o0*tx + o1*tyv + o2*tz + o3;
        }
    }

    // ---- segment product (lane 7: frames 28,29 only; 30,31 are leaves) ----
    float I[12];
    #pragma unroll
    for (int i = 0; i < 12; ++i) I[i] = M[0][i];
    #pragma unroll
    for (int j = 1; j < 4; ++j) {
        float N[12];
        amul(N, I, M[j]);
        const bool keep = !(sub == 7 && j >= 2);
        #pragma unroll
        for (int i = 0; i < 12; ++i) I[i] = keep ? N[i] : I[i];
    }

    // ---- 3-step inclusive scan over the 8 segments (shuffle, in-group) ----
    #pragma unroll
    for (int d = 1; d <= 4; d <<= 1) {
        const int src = grp | ((sub - d) & 7);
        float T[12];
        #pragma unroll
        for (int i = 0; i < 12; ++i) T[i] = __shfl(I[i], src, 64);
        float N[12];
        amul(N, T, I);
        const bool use = (sub >= d);
        #pragma unroll
        for (int i = 0; i < 12; ++i) I[i] = use ? N[i] : I[i];
    }

    // ---- exclusive prefix E = I_{sub-1} (identity at sub 0) ----
    const float ID[12] = {1,0,0,0, 0,1,0,0, 0,0,1,0};
    float run[12];
    {
        const int src = grp | ((sub - 1) & 7);
        #pragma unroll
        for (int i = 0; i < 12; ++i) {
            const float t = __shfl(I[i], src, 64);
            run[i] = (sub > 0) ? t : ID[i];
        }
    }

    // ---- pass 2: chain poses in place; capture pose_10 at lane 2 ----
    float P10[12];
    #pragma unroll
    for (int i = 0; i < 12; ++i) P10[i] = run[i];
    #pragma unroll
    for (int j = 0; j < 4; ++j) {
        float N[12];
        amul(N, run, M[j]);
        const bool chain = !(sub == 7 && j >= 2);
        #pragma unroll
        for (int i = 0; i < 12; ++i) {
            M[j][i] = chain ? N[i] : M[j][i];
            run[i]  = chain ? N[i] : run[i];
        }
        if (j == 2 && sub == 2) {
            #pragma unroll
            for (int i = 0; i < 12; ++i) P10[i] = N[i];   // frame 10
        }
    }
    // broadcast pose_10 from sublane 2; compose leaves 30,31 on lane 7
    #pragma unroll
    for (int i = 0; i < 12; ++i) P10[i] = __shfl(P10[i], grp | 2, 64);
    #pragma unroll
    for (int j = 2; j < 4; ++j) {
        float N[12];
        amul(N, P10, M[j]);
        #pragma unroll
        for (int i = 0; i < 12; ++i) M[j][i] = (sub == 7) ? N[i] : M[j][i];
    }

    // ---- intra-wave LDS transpose + fully-coalesced full-line stores ----
    float* const st = s_stage[wv];
    const long wbat0 = (long)blockIdx.x * 32 + wv * 8;
    float4* const out4 = (float4*)out;
    const int row = lane & 3;

    #pragma unroll
    for (int j = 0; j < 4; ++j) {
        float4* wp = (float4*)&st[lane * SLOT_DW];
        wp[0] = make_float4(M[j][0], M[j][1], M[j][2],  M[j][3]);
        wp[1] = make_float4(M[j][4], M[j][5], M[j][6],  M[j][7]);
        wp[2] = make_float4(M[j][8], M[j][9], M[j][10], M[j][11]);
        wp[3] = make_float4(0.0f, 0.0f, 0.0f, 1.0f);
        __builtin_amdgcn_wave_barrier();   // DS is in-order within a wave
        #pragma unroll
        for (int m = 0; m < 4; ++m) {
            const int  slot = m * 16 + (lane >> 2);
            const float4 v  = *(const float4*)&st[slot * SLOT_DW + row * 4];
            const long bb   = wbat0 + (slot >> 3);
            const int  fr   = 4 * (slot & 7) + j;
            if (bb < (long)B)
                out4[bb * 128 + fr * 4 + row] = v;   // 4-lane cluster = 1 full line
        }
        __builtin_amdgcn_wave_barrier();
    }
}

extern "C" void kernel_launch(void* const* d_in, const int* in_sizes, int n_in,
                              void* d_out, int out_size, void* d_ws, size_t ws_size,
                              hipStream_t stream) {
    const float* ja   = (const float*)d_in[0];
    const float* axes = (const float*)d_in[1];
    const float* orig = (const float*)d_in[2];
    const float* mmul = (const float*)d_in[3];
    const float* moff = (const float*)d_in[4];
    const int*   ctrl = (const int*)d_in[5];
    const int*   msrc = (const int*)d_in[6];
    const int*   mdst = (const int*)d_in[7];
    const int*   typs = (const int*)d_in[8];
    float* out = (float*)d_out;

    const int B = in_sizes[0] / NDOF;
    const int grid = (B + 31) / 32;     // 32 batches per block (8 lanes/batch)
    fk_kernel<<<grid, BLOCK, 0, stream>>>(ja, axes, orig, mmul, moff,
                                          ctrl, msrc, mdst, typs, out, B);
}